// Round 6
// baseline (649.437 us; speedup 1.0000x reference)
//
#include <hip/hip_runtime.h>
#include <math.h>

// ---- types ----------------------------------------------------------------
typedef __attribute__((ext_vector_type(8))) __bf16 bf16x8;   // MFMA A/B frag (4 VGPR)
typedef __attribute__((ext_vector_type(8))) short  short8;   // raw 16B store
typedef __attribute__((ext_vector_type(4))) unsigned short ushort4v;
typedef __attribute__((ext_vector_type(4))) float  floatx4;  // 16x16 C/D frag
typedef __attribute__((ext_vector_type(16))) float floatx16; // 32x32 C/D frag

typedef __attribute__((address_space(1))) unsigned int as1_u32;
typedef __attribute__((address_space(3))) unsigned int as3_u32;

// async global->LDS, 16B per lane, dest = uniform base + lane*16
__device__ __forceinline__ void async_copy16(const void* g, void* l) {
  __builtin_amdgcn_global_load_lds((const as1_u32*)g, (as3_u32*)l, 16, 0, 0);
}

__device__ __forceinline__ unsigned short f2bf(float f) {  // RNE float->bf16 bits
  union { float f; unsigned u; } v; v.f = f;
  unsigned r = v.u + 0x7fffu + ((v.u >> 16) & 1u);
  return (unsigned short)(r >> 16);
}

__device__ __forceinline__ floatx4 mfma_bf16(bf16x8 a, bf16x8 b, floatx4 c) {
  return __builtin_amdgcn_mfma_f32_16x16x32_bf16(a, b, c, 0, 0, 0);
}

__device__ __forceinline__ floatx16 mfma32(bf16x8 a, bf16x8 b, floatx16 c) {
  return __builtin_amdgcn_mfma_f32_32x32x16_bf16(a, b, c, 0, 0, 0);
}

__device__ __forceinline__ bf16x8 lds_frag(const unsigned short* p) {
  return *(const bf16x8*)(const void*)p;  // ds_read_b128
}

// ---- prep: all four f32->bf16 conversions in ONE launch --------------------
__global__ __launch_bounds__(256)
void prep(const float* __restrict__ x,  const float* __restrict__ wq,
          const float* __restrict__ wk, const float* __restrict__ wv,
          unsigned short* __restrict__ Xb, unsigned short* __restrict__ Wqb,
          unsigned short* __restrict__ Wkb, unsigned short* __restrict__ Wvb) {
  const int i = blockIdx.x * 256 + threadIdx.x;
  const float* s; unsigned short* d; int off;
  if (i < 2097152)             { s = x;  d = Xb;  off = i; }
  else if (i < 2097152+65536)  { s = wq; d = Wqb; off = i - 2097152; }
  else if (i < 2097152+131072) { s = wk; d = Wkb; off = i - (2097152+65536); }
  else                         { s = wv; d = Wvb; off = i - (2097152+131072); }
  const float4 v = ((const float4*)s)[off];
  ushort4v o;
  o.x = f2bf(v.x); o.y = f2bf(v.y); o.z = f2bf(v.z); o.w = f2bf(v.w);
  *(ushort4v*)(void*)(d + (size_t)off * 4) = o;
}

// ---- fused QKV GEMM: unchanged (verified) ----------------------------------
__global__ __launch_bounds__(256, 2)
void gemm_qkv(const unsigned short* __restrict__ Xb,
              const unsigned short* __restrict__ Wqb,
              const unsigned short* __restrict__ Wkb,
              const unsigned short* __restrict__ Wvb,
              unsigned short* __restrict__ Q,
              unsigned short* __restrict__ K,
              unsigned short* __restrict__ Vt) {
  const int gid = blockIdx.x;
  const unsigned short *A, *B; unsigned short* C;
  int m0, n0, N;
  if (gid < 512) {                        // Q = Xb · Wq^T
    A = Xb; B = Wqb; C = Q; N = 512;
    m0 = (gid & 127) * 128; n0 = (gid >> 7) * 128;
  } else if (gid < 1024) {                // K = Xb · Wk^T
    A = Xb; B = Wkb; C = K; N = 512;
    m0 = ((gid - 512) & 127) * 128; n0 = ((gid - 512) >> 7) * 128;
  } else {                                // V^T = Wv · Xb^T  (M=512, N=16384)
    A = Wvb; B = Xb; C = Vt; N = 16384;
    m0 = ((gid - 1024) & 3) * 128; n0 = ((gid - 1024) >> 2) * 128;
  }

  __shared__ unsigned short As[128 * 64];
  __shared__ unsigned short Bs[128 * 64];
  const int tid = threadIdx.x;
  const int w = tid >> 6, lane = tid & 63;
  const int quad = lane >> 4, l15 = lane & 15;
  const int wm = w >> 1, wn = w & 1;
  const int row_l = lane >> 3;
  const int chk   = lane & 7;
  const int s_chk = chk ^ row_l;          // swizzled SOURCE chunk

  floatx4 acc[16];
#pragma unroll
  for (int i = 0; i < 16; i++) acc[i] = (floatx4){0.f, 0.f, 0.f, 0.f};

  for (int kt = 0; kt < 8; kt++) {
    __syncthreads();
#pragma unroll
    for (int i = 0; i < 4; i++) {
      const int c = w * 4 + i;
      const int row = c * 8 + row_l;
      async_copy16(A + (size_t)(m0 + row) * 512 + kt * 64 + s_chk * 8, &As[c * 512]);
      async_copy16(B + (size_t)(n0 + row) * 512 + kt * 64 + s_chk * 8, &Bs[c * 512]);
    }
    __syncthreads();
#pragma unroll
    for (int kc = 0; kc < 2; kc++) {
      bf16x8 af[4], bfv[4];
#pragma unroll
      for (int i = 0; i < 4; i++) {
        const int pc = ((kc * 4 + quad) ^ (l15 & 7)) * 8;
        af[i]  = lds_frag(&As[(wm * 64 + i * 16 + l15) * 64 + pc]);
        bfv[i] = lds_frag(&Bs[(wn * 64 + i * 16 + l15) * 64 + pc]);
      }
#pragma unroll
      for (int mi = 0; mi < 4; mi++)
#pragma unroll
        for (int ni = 0; ni < 4; ni++)
          acc[mi * 4 + ni] = mfma_bf16(af[mi], bfv[ni], acc[mi * 4 + ni]);
    }
  }
#pragma unroll
  for (int mi = 0; mi < 4; mi++)
#pragma unroll
    for (int ni = 0; ni < 4; ni++)
#pragma unroll
      for (int r = 0; r < 4; r++) {
        const int row = m0 + wm * 64 + mi * 16 + quad * 4 + r;
        const int col = n0 + wn * 64 + ni * 16 + l15;
        C[(size_t)row * N + col] = f2bf(acc[mi * 4 + ni][r]);
      }
}

// ---- fused attention: 32x32x16 MFMA structure (round 6) --------------------
// R5 post-mortem: structure CORRECT (absmax bit-identical) but
// __launch_bounds__(512,2) resolved to a 128-VGPR cap; qf[32] alone is 128
// VGPRs -> the allocator spilled oacc/fragments to scratch (FETCH_SIZE
// 41->245 MB, WRITE_SIZE 33->99 MB, MfmaUtil 10%). The block is LDS-bound
// to 1 block/CU (153 KB) = 2 waves/SIMD, which supports 256 VGPRs/wave.
// Fix: __launch_bounds__(512,1) -- workgroup schedulability still caps the
// allocator at 256, occupancy unchanged, spill gone. Everything else
// byte-identical to the R5 correctness-verified kernel.
//   phase 1: S(64x64) = 4 tiles 32x32, waves 0-3 (one/SIMD), full K=512,
//            32 MFMA each; waves 4-7 issue V-DMA then wait.
//   phase 3: O(64x512) = 32 tiles 32x32 (K=64), all 8 waves x 4 tiles.
// Ks/Vs DMA + storage swizzle: phys chunk = logical ^ (row&7) (verified).
// Barrier/drain schedule: explicit vmcnt(0) before each publishing barrier;
// V flies under QK^T+softmax, K under PV (R4-verified pattern).
// 32x32 C/D layout: col=lane&31, row=(reg&3)+8*(reg>>2)+4*(lane>>5).
#define SCALE 0.044194173824159216f  // 1/sqrt(512)

__global__ __launch_bounds__(512, 1)
void attn_kernel(const unsigned short* __restrict__ Qg,
                 const unsigned short* __restrict__ Kg,
                 const unsigned short* __restrict__ Vt,   // [512][16384] = V^T
                 float* __restrict__ O) {                 // f32 output
  __shared__ unsigned short Ks[64 * 512];   // 64 KB: 64 keys x 512 feats (swizzled)
  __shared__ unsigned short Vs[512 * 64];   // 64 KB: 512 d x 64 keys (swizzled)
  __shared__ float Sx[64][65];              // 16.6 KB
  __shared__ unsigned short Pb[64 * 64];    //  8 KB (XOR-swizzled rows)
  __shared__ float m_row[64], l_row[64], a_row[64];

  const int tid = threadIdx.x;
  const int w = tid >> 6, lane = tid & 63;
  const int l31 = lane & 31, lh = lane >> 5, l7 = lane & 7;

  // XCD-contiguous swizzle: each XCD gets 32 consecutive logical blocks
  const int g0 = blockIdx.x;
  const int g  = (g0 & 7) * 32 + (g0 >> 3);   // 256 blocks, bijective
  const int b  = g >> 6;
  const int q0 = (g & 63) * 64;

  if (tid < 64) { m_row[tid] = -3.0e38f; l_row[tid] = 0.f; }

  const int wq2 = (w >> 1) & 1, wk = w & 1;       // phase-1 roles (waves 0-3)
  const int p2  = w >> 2, dbase = (w & 3) * 128;  // phase-3 roles (all waves)

  // Q A-fragments in registers: waves 0-3 only, 32 rows x full K=512 (128 VGPR)
  bf16x8 qf[32];
  if (w < 4) {
    const unsigned short* qrow = Qg + (size_t)(b * 4096 + q0 + wq2 * 32 + l31) * 512;
#pragma unroll
    for (int i = 0; i < 32; i++)
      qf[i] = *(const bf16x8*)(const void*)(qrow + i * 16 + lh * 8);
  }

  floatx16 oacc[4];   // 4 d-tiles of 32x32 per wave: 32q x 128d
#pragma unroll
  for (int j = 0; j < 4; j++)
#pragma unroll
    for (int r = 0; r < 16; r++) oacc[j][r] = 0.f;

  const unsigned short* kb0 = Kg + (size_t)b * 4096 * 512;
  const unsigned short* vb0 = Vt + (size_t)b * 4096;

  // K tile stage (all 8 waves): phys chunk p of row holds logical p^(row&7);
  // source pre-swizzled.
  auto issue_K = [&](int kt_) {
#pragma unroll
    for (int u = 0; u < 8; u++) {
      const int row = w * 8 + u;
      async_copy16(kb0 + ((size_t)kt_ * 64 + row) * 512 + (lane ^ u) * 8,
                   &Ks[row * 512]);
    }
  };
  // V tile stage: waves 4-7 only (16 issues each).
  const int v_d = lane >> 3, v_schk = (lane & 7) ^ v_d;
  auto issue_V = [&](int kt_) {
#pragma unroll
    for (int u = 0; u < 16; u++) {
      const int unit = (w - 4) * 16 + u;
      const int d = unit * 8 + v_d;
      async_copy16(vb0 + (size_t)kt_ * 64 + (size_t)d * 16384 + v_schk * 8,
                   &Vs[unit * 512]);
    }
  };

  const int srow = tid >> 3, sg = tid & 7;
  const int pb_wchunk = sg ^ (srow & 7);   // Pb write swizzle

  issue_K(0);   // prologue: K(0) in flight; published at B1 of kt=0

  for (int kt = 0; kt < 64; kt++) {
    // B1: publish Ks(kt). Explicit per-wave drain (R4-verified pattern).
    asm volatile("s_waitcnt vmcnt(0)" ::: "memory");
    __builtin_amdgcn_sched_barrier(0);
    __syncthreads();
    if (w >= 4) issue_V(kt);   // Vs dead since B1; flies under phase1+softmax

    // ---- phase 1 (waves 0-3): S-tile 32q x 32k, K=512, 32 MFMA(32x32x16)
    if (w < 4) {
      floatx16 sacc;
#pragma unroll
      for (int r = 0; r < 16; r++) sacc[r] = 0.f;
      const int krow = wk * 32 + l31;
#pragma unroll
      for (int i = 0; i < 32; i++) {
        bf16x8 kfr = lds_frag(&Ks[krow * 512 + (((i * 2 + lh) ^ l7) * 8)]);
        sacc = mfma32(qf[i], kfr, sacc);
      }
#pragma unroll
      for (int reg = 0; reg < 16; reg++) {
        const int rl = (reg & 3) + 8 * (reg >> 2) + 4 * lh;
        Sx[wq2 * 32 + rl][wk * 32 + l31] = sacc[reg] * SCALE;
      }
    }
    __syncthreads();        // B2: Sx visible (V DMA still in flight - ok)

    // ---- phase 2: online softmax (fp32), 8 lanes per q-row (unchanged)
    {
      float vals[8];
      float tmax = -3.0e38f;
#pragma unroll
      for (int j = 0; j < 8; j++) {
        float xv = Sx[srow][sg * 8 + j];
        xv = fminf(fmaxf(xv, -1.0e4f), 1.0e4f);
        vals[j] = xv;
        tmax = fmaxf(tmax, xv);
      }
      tmax = fmaxf(tmax, __shfl_xor(tmax, 1));
      tmax = fmaxf(tmax, __shfl_xor(tmax, 2));
      tmax = fmaxf(tmax, __shfl_xor(tmax, 4));
      const float m_old = m_row[srow];
      const float m_new = fmaxf(m_old, tmax);
      const float alpha = __expf(m_old - m_new);
      float lsum = 0.f;
      short8 pvec;
#pragma unroll
      for (int j = 0; j < 8; j++) {
        const float p = __expf(vals[j] - m_new);
        lsum += p;
        pvec[j] = (short)f2bf(p);
      }
      lsum += __shfl_xor(lsum, 1);
      lsum += __shfl_xor(lsum, 2);
      lsum += __shfl_xor(lsum, 4);
      *(short8*)(void*)&Pb[srow * 64 + pb_wchunk * 8] = pvec;
      if (sg == 0) {
        m_row[srow] = m_new;
        l_row[srow] = l_row[srow] * alpha + lsum;
        a_row[srow] = alpha;
      }
    }
    __syncthreads();        // B3: Pb, a_row visible (V DMA still in flight - ok)

    // ---- hoisted pre-PV work (no Vs access): O-rescale + P A-fragments
#pragma unroll
    for (int reg = 0; reg < 16; reg++) {
      const float a = a_row[p2 * 32 + (reg & 3) + 8 * (reg >> 2) + 4 * lh];
#pragma unroll
      for (int j = 0; j < 4; j++) oacc[j][reg] *= a;
    }
    bf16x8 pfr[4];
    {
      const int q = p2 * 32 + l31;   // q&7 == l7
#pragma unroll
      for (int kk = 0; kk < 4; kk++)
        pfr[kk] = lds_frag(&Pb[q * 64 + (((kk * 2 + lh) ^ l7) * 8)]);
    }

    // B4: publish Vs(kt).
    asm volatile("s_waitcnt vmcnt(0)" ::: "memory");
    __builtin_amdgcn_sched_barrier(0);
    __syncthreads();
    if (kt < 63) issue_K(kt + 1);   // Ks dead since B2; flies under phase 3

    // ---- phase 3 (all 8 waves): O += P V, 4 tiles x 4 MFMA(32x32x16)
#pragma unroll
    for (int j = 0; j < 4; j++) {
      const int d = dbase + j * 32 + l31;   // d&7 == l7
#pragma unroll
      for (int kk = 0; kk < 4; kk++) {
        bf16x8 vfr = lds_frag(&Vs[d * 64 + (((kk * 2 + lh) ^ l7) * 8)]);
        oacc[j] = mfma32(pfr[kk], vfr, oacc[j]);
      }
    }
  }

  // ---- epilogue: O / l, f32 store
  __syncthreads();
#pragma unroll
  for (int reg = 0; reg < 16; reg++) {
    const int rl = (reg & 3) + 8 * (reg >> 2) + 4 * lh;
    const float inv = 1.0f / l_row[p2 * 32 + rl];
    const int row = b * 4096 + q0 + p2 * 32 + rl;
#pragma unroll
    for (int j = 0; j < 4; j++)
      O[(size_t)row * 512 + dbase + j * 32 + l31] = oacc[j][reg] * inv;
  }
}

// ---- launch ---------------------------------------------------------------
extern "C" void kernel_launch(void* const* d_in, const int* in_sizes, int n_in,
                              void* d_out, int out_size, void* d_ws, size_t ws_size,
                              hipStream_t stream) {
  const float* x   = (const float*)d_in[0];
  const float* wqf = (const float*)d_in[1];
  const float* wkf = (const float*)d_in[2];
  const float* wvf = (const float*)d_in[3];

  unsigned short* Xb  = (unsigned short*)d_out;        // 16384 x 512 bf16 (dead before attn)
  unsigned short* Wqb = (unsigned short*)d_ws;         // 512 x 512
  unsigned short* Wkb = Wqb + (size_t)512 * 512;
  unsigned short* Wvb = Wkb + (size_t)512 * 512;
  unsigned short* Q   = Wvb + (size_t)512 * 512;       // 16384 x 512
  unsigned short* K   = Q + (size_t)16384 * 512;       // 16384 x 512
  unsigned short* Vt  = K + (size_t)16384 * 512;       // 512 x 16384 (V^T)

  prep<<<dim3(8960), 256, 0, stream>>>(x, wqf, wkf, wvf, Xb, Wqb, Wkb, Wvb);
  gemm_qkv<<<dim3(1536), 256, 0, stream>>>(Xb, Wqb, Wkb, Wvb, Q, K, Vt);
  attn_kernel<<<dim3(256), 512, 0, stream>>>(Q, K, Vt, (float*)d_out);
}

// Round 9
// 336.539 us; speedup vs baseline: 1.9298x; 1.9298x over previous
//
#include <hip/hip_runtime.h>
#include <math.h>

// ---- types ----------------------------------------------------------------
typedef __attribute__((ext_vector_type(8))) __bf16 bf16x8;   // MFMA A/B frag (4 VGPR)
typedef __attribute__((ext_vector_type(8))) short  short8;   // raw 16B store
typedef __attribute__((ext_vector_type(4))) unsigned short ushort4v;
typedef __attribute__((ext_vector_type(4))) float  floatx4;  // 16x16 C/D frag
typedef __attribute__((ext_vector_type(16))) float floatx16; // 32x32 C/D frag

typedef __attribute__((address_space(1))) unsigned int as1_u32;
typedef __attribute__((address_space(3))) unsigned int as3_u32;

// async global->LDS, 16B per lane, dest = uniform base + lane*16
__device__ __forceinline__ void async_copy16(const void* g, void* l) {
  __builtin_amdgcn_global_load_lds((const as1_u32*)g, (as3_u32*)l, 16, 0, 0);
}

__device__ __forceinline__ unsigned short f2bf(float f) {  // RNE float->bf16 bits
  union { float f; unsigned u; } v; v.f = f;
  unsigned r = v.u + 0x7fffu + ((v.u >> 16) & 1u);
  return (unsigned short)(r >> 16);
}

__device__ __forceinline__ floatx4 mfma_bf16(bf16x8 a, bf16x8 b, floatx4 c) {
  return __builtin_amdgcn_mfma_f32_16x16x32_bf16(a, b, c, 0, 0, 0);
}

__device__ __forceinline__ floatx16 mfma32(bf16x8 a, bf16x8 b, floatx16 c) {
  return __builtin_amdgcn_mfma_f32_32x32x16_bf16(a, b, c, 0, 0, 0);
}

__device__ __forceinline__ bf16x8 lds_frag(const unsigned short* p) {
  return *(const bf16x8*)(const void*)p;  // ds_read_b128
}

// ---- prep: all four f32->bf16 conversions in ONE launch --------------------
__global__ __launch_bounds__(256)
void prep(const float* __restrict__ x,  const float* __restrict__ wq,
          const float* __restrict__ wk, const float* __restrict__ wv,
          unsigned short* __restrict__ Xb, unsigned short* __restrict__ Wqb,
          unsigned short* __restrict__ Wkb, unsigned short* __restrict__ Wvb) {
  const int i = blockIdx.x * 256 + threadIdx.x;
  const float* s; unsigned short* d; int off;
  if (i < 2097152)             { s = x;  d = Xb;  off = i; }
  else if (i < 2097152+65536)  { s = wq; d = Wqb; off = i - 2097152; }
  else if (i < 2097152+131072) { s = wk; d = Wkb; off = i - (2097152+65536); }
  else                         { s = wv; d = Wvb; off = i - (2097152+131072); }
  const float4 v = ((const float4*)s)[off];
  ushort4v o;
  o.x = f2bf(v.x); o.y = f2bf(v.y); o.z = f2bf(v.z); o.w = f2bf(v.w);
  *(ushort4v*)(void*)(d + (size_t)off * 4) = o;
}

// ---- fused QKV GEMM: unchanged (verified) ----------------------------------
__global__ __launch_bounds__(256, 2)
void gemm_qkv(const unsigned short* __restrict__ Xb,
              const unsigned short* __restrict__ Wqb,
              const unsigned short* __restrict__ Wkb,
              const unsigned short* __restrict__ Wvb,
              unsigned short* __restrict__ Q,
              unsigned short* __restrict__ K,
              unsigned short* __restrict__ Vt) {
  const int gid = blockIdx.x;
  const unsigned short *A, *B; unsigned short* C;
  int m0, n0, N;
  if (gid < 512) {                        // Q = Xb · Wq^T
    A = Xb; B = Wqb; C = Q; N = 512;
    m0 = (gid & 127) * 128; n0 = (gid >> 7) * 128;
  } else if (gid < 1024) {                // K = Xb · Wk^T
    A = Xb; B = Wkb; C = K; N = 512;
    m0 = ((gid - 512) & 127) * 128; n0 = ((gid - 512) >> 7) * 128;
  } else {                                // V^T = Wv · Xb^T  (M=512, N=16384)
    A = Wvb; B = Xb; C = Vt; N = 16384;
    m0 = ((gid - 1024) & 3) * 128; n0 = ((gid - 1024) >> 2) * 128;
  }

  __shared__ unsigned short As[128 * 64];
  __shared__ unsigned short Bs[128 * 64];
  const int tid = threadIdx.x;
  const int w = tid >> 6, lane = tid & 63;
  const int quad = lane >> 4, l15 = lane & 15;
  const int wm = w >> 1, wn = w & 1;
  const int row_l = lane >> 3;
  const int chk   = lane & 7;
  const int s_chk = chk ^ row_l;          // swizzled SOURCE chunk

  floatx4 acc[16];
#pragma unroll
  for (int i = 0; i < 16; i++) acc[i] = (floatx4){0.f, 0.f, 0.f, 0.f};

  for (int kt = 0; kt < 8; kt++) {
    __syncthreads();
#pragma unroll
    for (int i = 0; i < 4; i++) {
      const int c = w * 4 + i;
      const int row = c * 8 + row_l;
      async_copy16(A + (size_t)(m0 + row) * 512 + kt * 64 + s_chk * 8, &As[c * 512]);
      async_copy16(B + (size_t)(n0 + row) * 512 + kt * 64 + s_chk * 8, &Bs[c * 512]);
    }
    __syncthreads();
#pragma unroll
    for (int kc = 0; kc < 2; kc++) {
      bf16x8 af[4], bfv[4];
#pragma unroll
      for (int i = 0; i < 4; i++) {
        const int pc = ((kc * 4 + quad) ^ (l15 & 7)) * 8;
        af[i]  = lds_frag(&As[(wm * 64 + i * 16 + l15) * 64 + pc]);
        bfv[i] = lds_frag(&Bs[(wn * 64 + i * 16 + l15) * 64 + pc]);
      }
#pragma unroll
      for (int mi = 0; mi < 4; mi++)
#pragma unroll
        for (int ni = 0; ni < 4; ni++)
          acc[mi * 4 + ni] = mfma_bf16(af[mi], bfv[ni], acc[mi * 4 + ni]);
    }
  }
#pragma unroll
  for (int mi = 0; mi < 4; mi++)
#pragma unroll
    for (int ni = 0; ni < 4; ni++)
#pragma unroll
      for (int r = 0; r < 4; r++) {
        const int row = m0 + wm * 64 + mi * 16 + quad * 4 + r;
        const int col = n0 + wn * 64 + ni * 16 + l15;
        C[(size_t)row * N + col] = f2bf(acc[mi * 4 + ni][r]);
      }
}

// ---- fused attention: 32x32 MFMA + split-K phase-1 (round 9 = round 7,
// resubmitted after two infra timeouts; kernel never ran) --------------------
// R5/R6 post-mortem: 512-thread workgroup = 8 waves on 4 SIMDs => 2 waves/SIMD
// REQUIRED => hard 256-reg (VGPR+AGPR) budget/wave. qf[32] (128) + oacc (64)
// + working (~80) > 256 -> spill (FETCH 230 MB, MfmaUtil 10%). Launch bounds
// cannot change this (R6: zero binary change). Fix: split phase-1 K across
// wave pairs.
//   phase 1: ALL 8 waves compute one of 4 32x32 S-tiles over HALF the
//            features (K=256, 16 MFMA, qf[16]=64 VGPR). Waves 0-3 write raw
//            partial to Sx; barrier; waves 4-7 do exclusive-ownership
//            read-add-scale (each element owned by one adder lane).
//   phase 3: O(64x512) = 32 tiles 32x32 (K=64), all 8 waves x 4 tiles (R5,
//            bit-verified).
// Ks/Vs/Pb swizzles, DMA schedule (explicit vmcnt(0) drain before publishing
// barriers; V flies under phase1+softmax, K under PV), hoisted rescale,
// epilogue: all identical to R4/R5 verified code.
// 32x32 C/D layout: col=lane&31, row=(reg&3)+8*(reg>>2)+4*(lane>>5).
// A/B layout: row/col=lane&31, k=(lane>>5)*8+e (R5 bit-verified).
#define SCALE 0.044194173824159216f  // 1/sqrt(512)

__global__ __launch_bounds__(512, 1)
void attn_kernel(const unsigned short* __restrict__ Qg,
                 const unsigned short* __restrict__ Kg,
                 const unsigned short* __restrict__ Vt,   // [512][16384] = V^T
                 float* __restrict__ O) {                 // f32 output
  __shared__ unsigned short Ks[64 * 512];   // 64 KB: 64 keys x 512 feats (swizzled)
  __shared__ unsigned short Vs[512 * 64];   // 64 KB: 512 d x 64 keys (swizzled)
  __shared__ float Sx[64][65];              // 16.6 KB
  __shared__ unsigned short Pb[64 * 64];    //  8 KB (XOR-swizzled rows)
  __shared__ float m_row[64], l_row[64], a_row[64];

  const int tid = threadIdx.x;
  const int w = tid >> 6, lane = tid & 63;
  const int l31 = lane & 31, lh = lane >> 5, l7 = lane & 7;

  // XCD-contiguous swizzle: each XCD gets 32 consecutive logical blocks
  const int g0 = blockIdx.x;
  const int g  = (g0 & 7) * 32 + (g0 >> 3);   // 256 blocks, bijective
  const int b  = g >> 6;
  const int q0 = (g & 63) * 64;

  if (tid < 64) { m_row[tid] = -3.0e38f; l_row[tid] = 0.f; }

  const int t  = w & 3;          // phase-1 tile: q-half t>>1, k(key)-half t&1
  const int gk = w >> 2;         // phase-1 feature-half (0: 0..255, 1: 256..511)
  const int p2 = w >> 2, dbase = (w & 3) * 128;  // phase-3 roles (R5)

  // Q A-fragments: 32 q-rows x 256 feats per wave (64 VGPR, no spill)
  bf16x8 qf[16];
  {
    const unsigned short* qrow =
        Qg + (size_t)(b * 4096 + q0 + (t >> 1) * 32 + l31) * 512;
#pragma unroll
    for (int i = 0; i < 16; i++)
      qf[i] = *(const bf16x8*)(const void*)(qrow + gk * 256 + i * 16 + lh * 8);
  }

  floatx16 oacc[4];   // 4 d-tiles of 32x32 per wave: 32q x 128d (AGPR)
#pragma unroll
  for (int j = 0; j < 4; j++)
#pragma unroll
    for (int r = 0; r < 16; r++) oacc[j][r] = 0.f;

  const unsigned short* kb0 = Kg + (size_t)b * 4096 * 512;
  const unsigned short* vb0 = Vt + (size_t)b * 4096;

  // K tile stage (all 8 waves): phys chunk p of row holds logical p^(row&7);
  // source pre-swizzled. (R2/R4/R5-verified)
  auto issue_K = [&](int kt_) {
#pragma unroll
    for (int u = 0; u < 8; u++) {
      const int row = w * 8 + u;
      async_copy16(kb0 + ((size_t)kt_ * 64 + row) * 512 + (lane ^ u) * 8,
                   &Ks[row * 512]);
    }
  };
  // V tile stage (all 8 waves, 8 issues each; R4-verified layout).
  const int v_d = lane >> 3, v_schk = (lane & 7) ^ v_d;
  auto issue_V = [&](int kt_) {
#pragma unroll
    for (int u = 0; u < 8; u++) {
      const int d = w * 64 + u * 8 + v_d;
      async_copy16(vb0 + (size_t)kt_ * 64 + (size_t)d * 16384 + v_schk * 8,
                   &Vs[(w * 64 + u * 8) * 64]);
    }
  };

  const int srow = tid >> 3, sg = tid & 7;
  const int pb_wchunk = sg ^ (srow & 7);   // Pb write swizzle (R5-verified)

  issue_K(0);   // prologue: K(0) in flight; published at B1 of kt=0

  for (int kt = 0; kt < 64; kt++) {
    // B1: publish Ks(kt). Explicit per-wave drain (R4-verified pattern).
    asm volatile("s_waitcnt vmcnt(0)" ::: "memory");
    __builtin_amdgcn_sched_barrier(0);
    __syncthreads();
    issue_V(kt);   // Vs dead since last phase 3; flies under phase1+softmax

    // ---- phase 1 (ALL waves): partial S-tile 32q x 32k over 256 feats,
    //      16 MFMA(32x32x16), two independent chains for ILP
    {
      floatx16 sa, sb;
#pragma unroll
      for (int r = 0; r < 16; r++) { sa[r] = 0.f; sb[r] = 0.f; }
      const int krow = (t & 1) * 32 + l31;   // krow&7 == l7
#pragma unroll
      for (int i = 0; i < 16; i += 2) {
        bf16x8 k0 = lds_frag(&Ks[krow * 512 + (((gk * 32 + i * 2 + lh) ^ l7) * 8)]);
        sa = mfma32(qf[i], k0, sa);
        bf16x8 k1 = lds_frag(&Ks[krow * 512 + (((gk * 32 + i * 2 + 2 + lh) ^ l7) * 8)]);
        sb = mfma32(qf[i + 1], k1, sb);
      }
#pragma unroll
      for (int r = 0; r < 16; r++) sa[r] += sb[r];

      if (w < 4) {   // writer half: raw partial
#pragma unroll
        for (int reg = 0; reg < 16; reg++) {
          const int rl = (reg & 3) + 8 * (reg >> 2) + 4 * lh;
          Sx[(t >> 1) * 32 + rl][(t & 1) * 32 + l31] = sa[reg];
        }
      }
      __syncthreads();   // B2a: writer partials visible
      if (w >= 4) {      // adder half: exclusive-ownership add + scale
#pragma unroll
        for (int reg = 0; reg < 16; reg++) {
          const int rl = (reg & 3) + 8 * (reg >> 2) + 4 * lh;
          float* p = &Sx[(t >> 1) * 32 + rl][(t & 1) * 32 + l31];
          *p = (*p + sa[reg]) * SCALE;
        }
      }
    }
    __syncthreads();   // B2b: Sx final (V DMA still in flight - ok)

    // ---- phase 2: online softmax (fp32), 8 lanes per q-row (unchanged)
    {
      float vals[8];
      float tmax = -3.0e38f;
#pragma unroll
      for (int j = 0; j < 8; j++) {
        float xv = Sx[srow][sg * 8 + j];
        xv = fminf(fmaxf(xv, -1.0e4f), 1.0e4f);
        vals[j] = xv;
        tmax = fmaxf(tmax, xv);
      }
      tmax = fmaxf(tmax, __shfl_xor(tmax, 1));
      tmax = fmaxf(tmax, __shfl_xor(tmax, 2));
      tmax = fmaxf(tmax, __shfl_xor(tmax, 4));
      const float m_old = m_row[srow];
      const float m_new = fmaxf(m_old, tmax);
      const float alpha = __expf(m_old - m_new);
      float lsum = 0.f;
      short8 pvec;
#pragma unroll
      for (int j = 0; j < 8; j++) {
        const float p = __expf(vals[j] - m_new);
        lsum += p;
        pvec[j] = (short)f2bf(p);
      }
      lsum += __shfl_xor(lsum, 1);
      lsum += __shfl_xor(lsum, 2);
      lsum += __shfl_xor(lsum, 4);
      *(short8*)(void*)&Pb[srow * 64 + pb_wchunk * 8] = pvec;
      if (sg == 0) {
        m_row[srow] = m_new;
        l_row[srow] = l_row[srow] * alpha + lsum;
        a_row[srow] = alpha;
      }
    }
    __syncthreads();        // B3: Pb, a_row visible (V DMA still in flight - ok)

    // ---- hoisted pre-PV work (no Vs access): O-rescale + P A-fragments (R5)
#pragma unroll
    for (int reg = 0; reg < 16; reg++) {
      const float a = a_row[p2 * 32 + (reg & 3) + 8 * (reg >> 2) + 4 * lh];
#pragma unroll
      for (int j = 0; j < 4; j++) oacc[j][reg] *= a;
    }
    bf16x8 pfr[4];
    {
      const int q = p2 * 32 + l31;   // q&7 == l7
#pragma unroll
      for (int kk = 0; kk < 4; kk++)
        pfr[kk] = lds_frag(&Pb[q * 64 + (((kk * 2 + lh) ^ l7) * 8)]);
    }

    // B4: publish Vs(kt).
    asm volatile("s_waitcnt vmcnt(0)" ::: "memory");
    __builtin_amdgcn_sched_barrier(0);
    __syncthreads();
    if (kt < 63) issue_K(kt + 1);   // Ks dead since B2; flies under phase 3

    // ---- phase 3 (all 8 waves): O += P V, 4 tiles x 4 MFMA(32x32x16) (R5)
#pragma unroll
    for (int j = 0; j < 4; j++) {
      const int d = dbase + j * 32 + l31;   // d&7 == l7
#pragma unroll
      for (int kk = 0; kk < 4; kk++) {
        bf16x8 vfr = lds_frag(&Vs[d * 64 + (((kk * 2 + lh) ^ l7) * 8)]);
        oacc[j] = mfma32(pfr[kk], vfr, oacc[j]);
      }
    }
  }

  // ---- epilogue: O / l, f32 store (R5)
  __syncthreads();
#pragma unroll
  for (int reg = 0; reg < 16; reg++) {
    const int rl = (reg & 3) + 8 * (reg >> 2) + 4 * lh;
    const float inv = 1.0f / l_row[p2 * 32 + rl];
    const int row = b * 4096 + q0 + p2 * 32 + rl;
#pragma unroll
    for (int j = 0; j < 4; j++)
      O[(size_t)row * 512 + dbase + j * 32 + l31] = oacc[j][reg] * inv;
  }
}

// ---- launch ---------------------------------------------------------------
extern "C" void kernel_launch(void* const* d_in, const int* in_sizes, int n_in,
                              void* d_out, int out_size, void* d_ws, size_t ws_size,
                              hipStream_t stream) {
  const float* x   = (const float*)d_in[0];
  const float* wqf = (const float*)d_in[1];
  const float* wkf = (const float*)d_in[2];
  const float* wvf = (const float*)d_in[3];

  unsigned short* Xb  = (unsigned short*)d_out;        // 16384 x 512 bf16 (dead before attn)
  unsigned short* Wqb = (unsigned short*)d_ws;         // 512 x 512
  unsigned short* Wkb = Wqb + (size_t)512 * 512;
  unsigned short* Wvb = Wkb + (size_t)512 * 512;
  unsigned short* Q   = Wvb + (size_t)512 * 512;       // 16384 x 512
  unsigned short* K   = Q + (size_t)16384 * 512;       // 16384 x 512
  unsigned short* Vt  = K + (size_t)16384 * 512;       // 512 x 16384 (V^T)

  prep<<<dim3(8960), 256, 0, stream>>>(x, wqf, wkf, wvf, Xb, Wqb, Wkb, Wvb);
  gemm_qkv<<<dim3(1536), 256, 0, stream>>>(Xb, Wqb, Wkb, Wvb, Q, K, Vt);
  attn_kernel<<<dim3(256), 512, 0, stream>>>(Q, K, Vt, (float*)d_out);
}